// Round 9
// baseline (85.327 us; speedup 1.0000x reference)
//
#include <hip/hip_runtime.h>

// out[s,i] = Re( U x_s ), reverse-order transposed-gate statevector sim.
// R9: 8 states/thread, 128-thread block (2 waves) per SV -> 4096 waves
// (4/SIMD, 2x R8) to hide LDS/barrier stalls. Per reversed layer
// (qubit q <-> bit 9-q; all 10 U3s commute, sigma applied first):
//   A: regs = bits 7-9 (q=2,1,0), sigma folded into gather reads
//   B: regs = bits 3,5,6 (q=6,4,3)  [bit 4 stays a thread bit so pass-B
//      bank-address rank is 5 -> <=2-way conflicts (free)]
//   C: regs = bits 0-2 (q=9,8,7), b128 LDS; then q=5 gate (SV bit 4 =
//      lane bit 1) via __shfl_xor(.,2) = DPP, no LDS round-trip.
//   Layer-0 pass C streams registers -> global (reals), coalesced.
// LDS: logical k at phys swz(k), swz(k)=k^((((k>>4)^(k>>7))&7)<<1)
// (involution, bits 1-3 only -> b64/b128 alignment preserved).

#define NQ 10
#define NL 5
#define NST 1024
#define NTH 128

typedef float f2 __attribute__((ext_vector_type(2)));

// Composed reversed-CNOT permutation (temporal chain, q=0 step first).
// Verified rounds 3/4/6/8. GF(2)-linear.
constexpr int csigma(int i) {
  for (int q = 0; q < NQ; ++q) {
    const int cb = 9 - q, tb = 9 - ((q + 1) % NQ);
    i ^= ((i >> cb) & 1) << tb;
  }
  return i;
}

__device__ __forceinline__ int swz(int k) {
  return k ^ ((((k >> 4) ^ (k >> 7)) & 7) << 1);
}

__global__ void build_gates(const float* __restrict__ w, float* __restrict__ gw) {
  const int t = threadIdx.x;
  if (t < NL * NQ) {
    const float th = w[t * 3 + 0], ph = w[t * 3 + 1], lm = w[t * 3 + 2];
    const float ch = cosf(0.5f * th), sh = sinf(0.5f * th);
    const float cl = cosf(lm), sl = sinf(lm);
    const float cp = cosf(ph), sp = sinf(ph);
    const float cpl = cosf(ph + lm), spl = sinf(ph + lm);
    float* G = gw + t * 8;  // transposed U3: h01=g10, h10=g01; h00 real
    G[0] = ch;       G[1] = 0.0f;
    G[2] = cp * sh;  G[3] = sp * sh;
    G[4] = -cl * sh; G[5] = -sl * sh;
    G[6] = cpl * ch; G[7] = spl * ch;
  }
}

// (a,b) <- H (a,b), h00 real. i*z = (-z.y, z.x).
__device__ __forceinline__ void bfly(f2& a, f2& b, const float h00,
                                     const float h01x, const float h01y,
                                     const float h10x, const float h10y,
                                     const float h11x, const float h11y) {
  const f2 ia = (f2){-a.y, a.x};
  const f2 ib = (f2){-b.y, b.x};
  const f2 na = h00 * a + h01x * b + h01y * ib;
  const f2 nb = h10x * a + h10y * ia + h11x * b + h11y * ib;
  a = na;
  b = nb;
}

#define LOAD_G(G)                                             \
  const float h00 = (G)[0];                                   \
  const float h01x = (G)[2], h01y = (G)[3];                   \
  const float h10x = (G)[4], h10y = (G)[5];                   \
  const float h11x = (G)[6], h11y = (G)[7];

__global__ __launch_bounds__(NTH) void qc_apply(
    const float* __restrict__ x, const float* __restrict__ gw,
    float* __restrict__ out, int out_size) {
  __shared__ alignas(16) f2 sc[NST];

  const int t = threadIdx.x;   // 7 bits
  const int sv = blockIdx.x;
  // swizzle mask for k = 8t+j (j<8): (k>>4)=t>>1, (k>>7)=t>>4
  const int mT = (((t >> 1) ^ (t >> 4)) & 7) << 1;

  // ---- init: logical k = 8t+j holds x[k], imag 0. phys pair = (8t+j0)^mT.
  {
    const float* xs = x + (size_t)sv * NST;
    const float4 x0 = ((const float4*)xs)[2 * t];
    const float4 x1 = ((const float4*)xs)[2 * t + 1];
    *(float4*)&sc[(8 * t + 0) ^ mT] = make_float4(x0.x, 0.f, x0.y, 0.f);
    *(float4*)&sc[(8 * t + 2) ^ mT] = make_float4(x0.z, 0.f, x0.w, 0.f);
    *(float4*)&sc[(8 * t + 4) ^ mT] = make_float4(x1.x, 0.f, x1.y, 0.f);
    *(float4*)&sc[(8 * t + 6) ^ mT] = make_float4(x1.z, 0.f, x1.w, 0.f);
  }
  __syncthreads();

  // sigma: runtime image of the 7 thread bits + constexpr images of bits 7-9.
  int sL = t;
#pragma unroll
  for (int q = 0; q < NQ; ++q) {
    const int cb = 9 - q, tb = 9 - ((q + 1) % NQ);
    sL ^= ((sL >> cb) & 1) << tb;
  }
  constexpr int SH7 = csigma(1 << 7), SH8 = csigma(1 << 8),
                SH9 = csigma(1 << 9);

  f2 v[8];

#pragma unroll 1
  for (int l = NL - 1; l >= 0; --l) {
    const float* gl = gw + l * NQ * 8;

    // ======== pass A: sigma gather; regs = bits 7-9, thread = bits 0-6.
#pragma unroll
    for (int r = 0; r < 8; ++r) {
      const int idx = sL ^ ((r & 1) ? SH7 : 0) ^ ((r & 2) ? SH8 : 0) ^
                      ((r & 4) ? SH9 : 0);
      v[r] = sc[swz(idx)];
    }
#pragma unroll
    for (int e = 0; e < 3; ++e) {   // reg bit e = SV bit 7+e <-> qubit 2-e
      LOAD_G(gl + (2 - e) * 8)
#pragma unroll
      for (int r = 0; r < 8; ++r)
        if (!(r & (1 << e)))
          bfly(v[r], v[r | (1 << e)], h00, h01x, h01y, h10x, h10y, h11x, h11y);
    }
    __syncthreads();  // all gathers done before layout change
#pragma unroll
    for (int r = 0; r < 8; ++r) sc[swz((r << 7) | t)] = v[r];
    __syncthreads();

    // ======== pass B: regs = bits 3,5,6; thread = bits 0-2,4,7-9.
    const int bbase = (t & 7) | (((t >> 3) & 1) << 4) | ((t >> 4) << 7);
#pragma unroll
    for (int r = 0; r < 8; ++r) {
      const int idx = bbase | ((r & 1) << 3) | (((r >> 1) & 1) << 5) |
                      (((r >> 2) & 1) << 6);
      v[r] = sc[swz(idx)];
    }
    {
      // reg bit 0 = SV bit 3 (q=6); bit 1 = SV bit 5 (q=4); bit 2 = SV bit 6 (q=3)
      const int GQ[3] = {6, 4, 3};
#pragma unroll
      for (int e = 0; e < 3; ++e) {
        LOAD_G(gl + GQ[e] * 8)
#pragma unroll
        for (int r = 0; r < 8; ++r)
          if (!(r & (1 << e)))
            bfly(v[r], v[r | (1 << e)], h00, h01x, h01y, h10x, h10y, h11x, h11y);
      }
    }
#pragma unroll
    for (int r = 0; r < 8; ++r) {
      const int idx = bbase | ((r & 1) << 3) | (((r >> 1) & 1) << 5) |
                      (((r >> 2) & 1) << 6);
      sc[swz(idx)] = v[r];
    }
    __syncthreads();

    // ======== pass C: regs = bits 0-2 (contiguous, b128); thread = bits 3-9.
#pragma unroll
    for (int j0 = 0; j0 < 8; j0 += 2) {
      const float4 p = *(const float4*)&sc[(8 * t + j0) ^ mT];
      v[j0]     = (f2){p.x, p.y};
      v[j0 + 1] = (f2){p.z, p.w};
    }
#pragma unroll
    for (int e = 0; e < 3; ++e) {   // reg bit e = SV bit e <-> qubit 9-e
      LOAD_G(gl + (9 - e) * 8)
#pragma unroll
      for (int r = 0; r < 8; ++r)
        if (!(r & (1 << e)))
          bfly(v[r], v[r | (1 << e)], h00, h01x, h01y, h10x, h10y, h11x, h11y);
    }
    // q=5 gate on SV bit 4 = thread bit 1 = lane bit 1: __shfl_xor mask 2.
    {
      LOAD_G(gl + 5 * 8)
      const bool hi = (t >> 1) & 1;   // holds the '1' branch of SV bit 4
      const float c1 = hi ? h11x : h00;
      const float c2 = hi ? h11y : 0.0f;
      const float c3 = hi ? h10x : h01x;
      const float c4 = hi ? h10y : h01y;
#pragma unroll
      for (int r = 0; r < 8; ++r) {
        f2 p;
        p.x = __shfl_xor(v[r].x, 2);
        p.y = __shfl_xor(v[r].y, 2);
        const f2 iv = (f2){-v[r].y, v[r].x};
        const f2 ip = (f2){-p.y, p.x};
        v[r] = c1 * v[r] + c2 * iv + c3 * p + c4 * ip;
      }
    }
    if (l != 0) {
#pragma unroll
      for (int j0 = 0; j0 < 8; j0 += 2)
        *(float4*)&sc[(8 * t + j0) ^ mT] =
            make_float4(v[j0].x, v[j0].y, v[j0 + 1].x, v[j0 + 1].y);
      __syncthreads();
    }
  }

  // ---- layer-0 pass-C results: registers -> global (reals), coalesced.
  const size_t ob = (size_t)sv * NST + 8 * t;
  if (ob + 8 <= (size_t)out_size) {
    *(float4*)(out + ob)     = make_float4(v[0].x, v[1].x, v[2].x, v[3].x);
    *(float4*)(out + ob + 4) = make_float4(v[4].x, v[5].x, v[6].x, v[7].x);
  }
}

extern "C" void kernel_launch(void* const* d_in, const int* in_sizes, int n_in,
                              void* d_out, int out_size, void* d_ws, size_t ws_size,
                              hipStream_t stream) {
  const float* x = (const float*)d_in[0];   // [128,16,32,32] f32
  const float* w = (const float*)d_in[1];   // [5,10,3] f32
  float* out = (float*)d_out;               // f32 (real part of complex64)
  float* gw = (float*)d_ws;                 // 50 gates x 8 floats = 1600 B
  const int nstates = in_sizes[0] / NST;    // 2048
  build_gates<<<1, 64, 0, stream>>>(w, gw);
  qc_apply<<<nstates, NTH, 0, stream>>>(x, gw, out, out_size);
}

// Round 11
// 84.364 us; speedup vs baseline: 1.0114x; 1.0114x over previous
//
#include <hip/hip_runtime.h>

// out[s,i] = Re( U x_s ), reverse-order transposed-gate statevector sim.
// R11 = R10 + one-line init fix. 16 st/thread, 64-thread block = 1 wave =
// 1 SV, grid 2048 (2 waves/SIMD). Per reversed layer (qubit q <-> bit 9-q),
// three register residencies / LDS round-trips:
//   RT1: regs = bits 6-9 (q=3..0); sigma folded into the gather, whose
//        addresses are A0 ^ constexpr[r] (sigma, layout, swizzle all linear).
//   RT2: regs = bits 2-5 (q=7..4); reads/writes are base|const (folds).
//   RT3: regs = bits 0,1,8,9; gates q=9,8; layer-0 streams regs -> global.
// Three layouts A/B/C cycle so every pass's addresses are layer-invariant.
// swz(p)=p^((((p>>4)^(p>>7))&7)<<1).
// R11 fix: init's second float4 must go to phys pa ^ 2 (swz XORs bit 1),
// not pa + 2 — the R5 bug class, reintroduced in R10. Half the quads left
// stale LDS garbage -> absmax 724.

#define NQ 10
#define NL 5
#define NST 1024
#define NTH 64

typedef float f2 __attribute__((ext_vector_type(2)));

// Composed reversed-CNOT permutation (temporal chain, q=0 step first).
// Verified rounds 3/4/6/8/9. GF(2)-linear.
constexpr int csigma(int i) {
  for (int q = 0; q < NQ; ++q) {
    const int cb = 9 - q, tb = 9 - ((q + 1) % NQ);
    i ^= ((i >> cb) & 1) << tb;
  }
  return i;
}

constexpr int cswz(int p) { return p ^ ((((p >> 4) ^ (p >> 7)) & 7) << 1); }
constexpr int crawA(int j) {
  return (((j >> 2) & 63) << 4) | (j & 3) | (((j >> 8) & 3) << 2);
}
// constexpr gather offsets: cswz(crawA(csigma(r<<6))), r = 0..15
constexpr int SRv(int r) { return cswz(crawA(csigma(r << 6))); }

__device__ __forceinline__ int swz(int p) {
  return p ^ ((((p >> 4) ^ (p >> 7)) & 7) << 1);
}
__device__ __forceinline__ int rawA(int j) {
  return (((j >> 2) & 63) << 4) | (j & 3) | (((j >> 8) & 3) << 2);
}

__global__ void build_gates(const float* __restrict__ w, float* __restrict__ gw) {
  const int t = threadIdx.x;
  if (t < NL * NQ) {
    const float th = w[t * 3 + 0], ph = w[t * 3 + 1], lm = w[t * 3 + 2];
    const float ch = cosf(0.5f * th), sh = sinf(0.5f * th);
    const float cl = cosf(lm), sl = sinf(lm);
    const float cp = cosf(ph), sp = sinf(ph);
    const float cpl = cosf(ph + lm), spl = sinf(ph + lm);
    float* G = gw + t * 8;  // transposed U3: h01=g10, h10=g01; h00 real
    G[0] = ch;       G[1] = 0.0f;
    G[2] = cp * sh;  G[3] = sp * sh;
    G[4] = -cl * sh; G[5] = -sl * sh;
    G[6] = cpl * ch; G[7] = spl * ch;
  }
}

// (a,b) <- H (a,b), h00 real. i*z = (-z.y, z.x).
__device__ __forceinline__ void bfly(f2& a, f2& b, const float h00,
                                     const float h01x, const float h01y,
                                     const float h10x, const float h10y,
                                     const float h11x, const float h11y) {
  const f2 ia = (f2){-a.y, a.x};
  const f2 ib = (f2){-b.y, b.x};
  const f2 na = h00 * a + h01x * b + h01y * ib;
  const f2 nb = h10x * a + h10y * ia + h11x * b + h11y * ib;
  a = na;
  b = nb;
}

#define LOAD_G(G)                                             \
  const float h00 = (G)[0];                                   \
  const float h01x = (G)[2], h01y = (G)[3];                   \
  const float h10x = (G)[4], h10y = (G)[5];                   \
  const float h11x = (G)[6], h11y = (G)[7];

__global__ __launch_bounds__(NTH) void qc_apply(
    const float* __restrict__ x, const float* __restrict__ gw,
    float* __restrict__ out, int out_size) {
  __shared__ alignas(16) f2 sc[NST];

  const int t = threadIdx.x;   // 6 bits; role changes per RT
  const int sv = blockIdx.x;

  // ---- init into layout A: logical k at swz(rawA(k)).
  // Quad k..k+3 lands at pa, pa^1, pa^2, pa^3 (swz XORs bit 1!).
  {
    const float* xs = x + (size_t)sv * NST;
#pragma unroll
    for (int i4 = 0; i4 < 4; ++i4) {
      const float4 xv = ((const float4*)xs)[4 * t + i4];
      const int k = 16 * t + 4 * i4;
      const int pa = swz(rawA(k));   // even
      *(float4*)&sc[pa]     = make_float4(xv.x, 0.f, xv.y, 0.f);
      *(float4*)&sc[pa ^ 2] = make_float4(xv.z, 0.f, xv.w, 0.f);
    }
  }
  __syncthreads();

  // sigma-gather base: A0 = swz(rawA(sigma(t))) for the 6 thread bits.
  int st = t;
#pragma unroll
  for (int q = 0; q < NQ; ++q) {
    const int cb = 9 - q, tb = 9 - ((q + 1) % NQ);
    st ^= ((st >> cb) & 1) << tb;
  }
  const int A0 = swz(rawA(st));
  static constexpr int SR[16] = {
      SRv(0),  SRv(1),  SRv(2),  SRv(3),  SRv(4),  SRv(5),  SRv(6),  SRv(7),
      SRv(8),  SRv(9),  SRv(10), SRv(11), SRv(12), SRv(13), SRv(14), SRv(15)};

  // Pass-invariant bases (layer-invariant; compiler hoists).
  const int WB = ((t & 3) << 4) | ((t >> 2) & 15);            // RT1 write, layout B
  const int RB = (((t >> 2) & 15) << 6) | ((t & 3) << 4);     // RT2 read,  layout B
  const int j69 = (t >> 2) & 15;
  const int WC = ((j69 & 3) << 8) | (t & 3) | (((j69 >> 2) & 3) << 2);  // RT2 write, C
  const int RC = (((t >> 4) & 3) << 8) | ((t & 15) << 4);     // RT3 read,  layout C
  const int WA = t << 4;                                      // RT3 write, layout A

  f2 v[16];

  for (int l = NL - 1; l >= 0; --l) {
    const float* gl = gw + l * NQ * 8;

    // ======== RT1: sigma gather; regs = bits 6-9 (qubits 3..0).
#pragma unroll
    for (int r = 0; r < 16; ++r) v[r] = sc[A0 ^ SR[r]];
#pragma unroll
    for (int e = 0; e < 4; ++e) {   // reg bit e = SV bit 6+e <-> qubit 3-e
      LOAD_G(gl + (3 - e) * 8)
#pragma unroll
      for (int r = 0; r < 16; ++r)
        if (!(r & (1 << e)))
          bfly(v[r], v[r | (1 << e)], h00, h01x, h01y, h10x, h10y, h11x, h11y);
    }
    __syncthreads();
#pragma unroll
    for (int r = 0; r < 16; ++r) sc[swz(WB | (r << 6))] = v[r];
    __syncthreads();

    // ======== RT2: regs = bits 2-5 (qubits 7..4); thread = bits 0,1,6-9.
#pragma unroll
    for (int r = 0; r < 16; ++r) v[r] = sc[swz(RB | r)];
#pragma unroll
    for (int e = 0; e < 4; ++e) {   // reg bit e = SV bit 2+e <-> qubit 7-e
      LOAD_G(gl + (7 - e) * 8)
#pragma unroll
      for (int r = 0; r < 16; ++r)
        if (!(r & (1 << e)))
          bfly(v[r], v[r | (1 << e)], h00, h01x, h01y, h10x, h10y, h11x, h11y);
    }
    __syncthreads();
#pragma unroll
    for (int r = 0; r < 16; ++r) sc[swz(WC | (r << 4))] = v[r];
    __syncthreads();

    // ======== RT3: regs = bits 0,1 (q=9,8) + carry bits 8,9; thread = bits 2-7.
#pragma unroll
    for (int r = 0; r < 16; ++r) v[r] = sc[swz(RC | r)];
    {
      LOAD_G(gl + 9 * 8)  // qubit 9 on reg bit 0
#pragma unroll
      for (int r = 0; r < 16; ++r)
        if (!(r & 1))
          bfly(v[r], v[r | 1], h00, h01x, h01y, h10x, h10y, h11x, h11y);
    }
    {
      LOAD_G(gl + 8 * 8)  // qubit 8 on reg bit 1
#pragma unroll
      for (int r = 0; r < 16; ++r)
        if (!(r & 2))
          bfly(v[r], v[r | 2], h00, h01x, h01y, h10x, h10y, h11x, h11y);
    }
    if (l != 0) {
      __syncthreads();
#pragma unroll
      for (int r = 0; r < 16; ++r) sc[swz(WA | r)] = v[r];
      __syncthreads();
    }
  }

  // ---- output: thread t holds j = (r&3) | t<<2 | (r>>2)<<8. Reals, coalesced.
  const size_t ob = (size_t)sv * NST;
#pragma unroll
  for (int h = 0; h < 4; ++h) {
    const size_t o = ob + (size_t)(h << 8) + (t << 2);
    if (o + 4 <= (size_t)out_size)
      *(float4*)(out + o) = make_float4(v[4 * h].x, v[4 * h + 1].x,
                                        v[4 * h + 2].x, v[4 * h + 3].x);
  }
}

extern "C" void kernel_launch(void* const* d_in, const int* in_sizes, int n_in,
                              void* d_out, int out_size, void* d_ws, size_t ws_size,
                              hipStream_t stream) {
  const float* x = (const float*)d_in[0];   // [128,16,32,32] f32
  const float* w = (const float*)d_in[1];   // [5,10,3] f32
  float* out = (float*)d_out;               // f32 (real part of complex64)
  float* gw = (float*)d_ws;                 // 50 gates x 8 floats = 1600 B
  const int nstates = in_sizes[0] / NST;    // 2048
  build_gates<<<1, 64, 0, stream>>>(w, gw);
  qc_apply<<<nstates, NTH, 0, stream>>>(x, gw, out, out_size);
}

// Round 12
// 82.309 us; speedup vs baseline: 1.0367x; 1.0250x over previous
//
#include <hip/hip_runtime.h>
#include <hip/hip_fp16.h>

// out[s,i] = Re( U x_s ), reverse-order transposed-gate statevector sim.
// R12: SoA-packed registers + f16 LDS + barrier-free single-wave blocks.
// 16 states/thread as 8 pairs packed on SV bit 9: vre[p]=(re_j, re_{j|512}),
// vim likewise -> gate butterflies are component-wise float2 FMA chains
// (v_pk_fma_f32), no swizzles. Per reversed layer (qubit q <-> bit 9-q):
//   RT1: reg bits 6-8 (q=3,2,1), sigma folded into the gather
//   RT2: reg bits 3-5 (q=6,5,4)
//   RT3: reg bits 0-2 (q=9,8,7) + bit-9 gate (q=0) scalar across pack halves
// LDS 4KB, f16 blocks of 8B. Layout A (layer boundary) pairs (s, s^511) with
// half h(s)=s0^s9 = bit9(sigma^-1(s)) so h(sigma(k))=bit9(k): the sigma-gather
// is 8 plain b64 reads per thread, no selection. Layouts B (RT1->RT2) and
// C (RT2->RT3) pair (p, p|512). All lane->bank maps rank-5 (conflict-free).
// No __syncthreads: 1 wave/block; same-wave DS ops execute in program order.

#define NQ 10
#define NL 5
#define NTH 64

typedef float f2 __attribute__((ext_vector_type(2)));
typedef unsigned int u32;

// ----- composed reversed ring-CNOT permutation (verified R3-R11), linear.
constexpr int csigma(int i) {
  for (int q = 0; q < NQ; ++q) {
    const int cb = 9 - q, tb = 9 - ((q + 1) % NQ);
    i ^= ((i >> cb) & 1) << tb;
  }
  return i;
}

// Layout-A block index (9 bits, linear, kernel {0,511}):
// A = [s0^s4, s1^s5, s2^s6, s3^s7, s4^s8, s0^s1, s1^s2, s2^s3, s9]
constexpr int cA(int s) {
  return ((s ^ (s >> 4)) & 1) | ((((s >> 1) ^ (s >> 5)) & 1) << 1) |
         ((((s >> 2) ^ (s >> 6)) & 1) << 2) |
         ((((s >> 3) ^ (s >> 7)) & 1) << 3) |
         ((((s >> 4) ^ (s >> 8)) & 1) << 4) | (((s ^ (s >> 1)) & 1) << 5) |
         ((((s >> 1) ^ (s >> 2)) & 1) << 6) |
         ((((s >> 2) ^ (s >> 3)) & 1) << 7) | (((s >> 9) & 1) << 8);
}
// Layout-C block index (linear, bijective on 9 bits):
// C = [p6, p7, p8, p0^p3, p1^p4, p2, p3, p4, p5]
constexpr int cC(int p) {
  return ((p >> 6) & 7) | (((p ^ (p >> 3)) & 1) << 3) |
         ((((p >> 1) ^ (p >> 4)) & 1) << 4) | (((p >> 2) & 1) << 5) |
         (((p >> 3) & 1) << 6) | (((p >> 4) & 1) << 7) | (((p >> 5) & 1) << 8);
}

__global__ void build_gates(const float* __restrict__ w, float* __restrict__ gw) {
  const int t = threadIdx.x;
  if (t < NL * NQ) {
    const float th = w[t * 3 + 0], ph = w[t * 3 + 1], lm = w[t * 3 + 2];
    const float ch_ = cosf(0.5f * th), sh = sinf(0.5f * th);
    const float cl = cosf(lm), sl = sinf(lm);
    const float cp = cosf(ph), sp = sinf(ph);
    const float cpl = cosf(ph + lm), spl = sinf(ph + lm);
    float* G = gw + t * 8;  // transposed U3: h01=g10, h10=g01; h00 real
    G[0] = ch_;       G[1] = 0.0f;
    G[2] = cp * sh;   G[3] = sp * sh;
    G[4] = -cl * sh;  G[5] = -sl * sh;
    G[6] = cpl * ch_; G[7] = spl * ch_;
  }
}

// packed SoA butterfly: two independent complex bflys, component-wise.
__device__ __forceinline__ void pbfly(f2& aRe, f2& aIm, f2& bRe, f2& bIm,
                                      float h00, float h01x, float h01y,
                                      float h10x, float h10y, float h11x,
                                      float h11y) {
  const f2 naRe = h00 * aRe + h01x * bRe - h01y * bIm;
  const f2 naIm = h00 * aIm + h01x * bIm + h01y * bRe;
  const f2 nbRe = h10x * aRe - h10y * aIm + h11x * bRe - h11y * bIm;
  const f2 nbIm = h10x * aIm + h10y * aRe + h11x * bIm + h11y * bRe;
  aRe = naRe; aIm = naIm; bRe = nbRe; bIm = nbIm;
}

__device__ __forceinline__ u32 pk2(float a, float b) {
  __half2 h = __floats2half2_rn(a, b);
  return *(u32*)&h;
}
__device__ __forceinline__ f2 up2(u32 u) {
  __half2 h = *(__half2*)&u;
  return (f2){__low2float(h), __high2float(h)};
}

__global__ __launch_bounds__(NTH) void qc_apply(
    const float* __restrict__ x, const float* __restrict__ gw,
    float* __restrict__ out, int out_size) {
  __shared__ alignas(16) u32 sc[1024];  // 512 blocks x 2 words (f16x2 each)

  const int t = threadIdx.x;
  const int sv = blockIdx.x;

  // ---- runtime sigma(t) (verified loop) and hoisted address bases.
  int st = t;
#pragma unroll
  for (int q = 0; q < NQ; ++q) {
    const int cb = 9 - q, tb = 9 - ((q + 1) % NQ);
    st ^= ((st >> cb) & 1) << tb;
  }
  const int baseS = cA(st) << 1;                 // sigma-read base (layout A)
  const int tb1 = t << 1;                        // RT1-write base (layout B)
  const int tb2 = (((t & 7) | ((t >> 3) << 6)) ^ ((((t >> 3) & 3)) << 3)) << 1;
  const int tc2 = cC((t & 7) | ((t >> 3) << 6)) << 1;  // RT2-write base (C)
  const int tc3 = cC(t << 3) << 1;               // RT3-read base (C)
  const int ta3 = cA(t << 3) << 1;               // RT3-write base (A)

  static constexpr int SRC[8] = {
      cA(csigma(0 << 6)) << 1, cA(csigma(1 << 6)) << 1, cA(csigma(2 << 6)) << 1,
      cA(csigma(3 << 6)) << 1, cA(csigma(4 << 6)) << 1, cA(csigma(5 << 6)) << 1,
      cA(csigma(6 << 6)) << 1, cA(csigma(7 << 6)) << 1};
#define CB1v(r) ((((r) << 6) ^ (((r) & 3) << 3)) << 1)
  static constexpr int CB1[8] = {CB1v(0), CB1v(1), CB1v(2), CB1v(3),
                                 CB1v(4), CB1v(5), CB1v(6), CB1v(7)};
  static constexpr int CC2[8] = {cC(0 << 3) << 1, cC(1 << 3) << 1,
                                 cC(2 << 3) << 1, cC(3 << 3) << 1,
                                 cC(4 << 3) << 1, cC(5 << 3) << 1,
                                 cC(6 << 3) << 1, cC(7 << 3) << 1};
  static constexpr int CC3[8] = {cC(0) << 1, cC(1) << 1, cC(2) << 1,
                                 cC(3) << 1, cC(4) << 1, cC(5) << 1,
                                 cC(6) << 1, cC(7) << 1};
  static constexpr int CWA[8] = {
      (cA(0) << 1) | 0, (cA(1) << 1) | 1, (cA(2) << 1) | 0, (cA(3) << 1) | 1,
      (cA(4) << 1) | 0, (cA(5) << 1) | 1, (cA(6) << 1) | 0, (cA(7) << 1) | 1};
  static constexpr int CAj[16] = {cA(0),  cA(1),  cA(2),  cA(3),
                                  cA(4),  cA(5),  cA(6),  cA(7),
                                  cA(8),  cA(9),  cA(10), cA(11),
                                  cA(12), cA(13), cA(14), cA(15)};

  // ---- init: x real -> layout A f16 (state s at word 2*A(s)+h(s), h=s0^s9).
  {
    const float* xs = x + (size_t)sv * 1024;
    float4 xv[4];
#pragma unroll
    for (int i4 = 0; i4 < 4; ++i4) xv[i4] = ((const float4*)xs)[4 * t + i4];
    const int ib2 = cA(16 * t) << 1;
    const int ihb = (t >> 5) & 1;  // h(16t) = s9 = t5
#pragma unroll
    for (int j = 0; j < 16; ++j) {
      const float xj = ((const float*)xv)[j];
      const int word = (ib2 ^ (CAj[j] << 1)) | (ihb ^ (j & 1));
      sc[word] = pk2(xj, 0.0f);
    }
  }

  f2 vre[8], vim[8];

  for (int l = NL - 1; l >= 0; --l) {
    const float* gl = gw + l * NQ * 8;

    // ======== RT1: sigma-gather (layout A); reg bits = SV bits 6-8.
    // Block at A(sigma(k)) holds [sigma(k) | sigma(k)^511] = the new pair.
#pragma unroll
    for (int r = 0; r < 8; ++r) {
      const uint2 b = *(const uint2*)&sc[baseS ^ SRC[r]];
      const f2 lo = up2(b.x);  // (re,im) of new lo state (bit9=0)
      const f2 hi = up2(b.y);  // (re,im) of new hi state (bit9=1)
      vre[r] = (f2){lo.x, hi.x};
      vim[r] = (f2){lo.y, hi.y};
    }
    {
      const int qb[3] = {3, 2, 1};  // reg bit e = SV bit 6+e <-> qubit 3-e
#pragma unroll
      for (int e = 0; e < 3; ++e) {
        const float* G = gl + qb[e] * 8;
        const float h00 = G[0], h01x = G[2], h01y = G[3], h10x = G[4],
                    h10y = G[5], h11x = G[6], h11y = G[7];
        const int m = 1 << e;
#pragma unroll
        for (int r = 0; r < 8; ++r)
          if (!(r & m))
            pbfly(vre[r], vim[r], vre[r | m], vim[r | m], h00, h01x, h01y,
                  h10x, h10y, h11x, h11y);
      }
    }
#pragma unroll
    for (int r = 0; r < 8; ++r) {
      uint2 b;
      b.x = pk2(vre[r].x, vre[r].y);
      b.y = pk2(vim[r].x, vim[r].y);
      *(uint2*)&sc[tb1 ^ CB1[r]] = b;
    }

    // ======== RT2 (layout B -> C); reg bits = SV bits 3-5.
#pragma unroll
    for (int r = 0; r < 8; ++r) {
      const uint2 b = *(const uint2*)&sc[tb2 ^ (r << 4)];
      vre[r] = up2(b.x);
      vim[r] = up2(b.y);
    }
    {
      const int qb[3] = {6, 5, 4};  // reg bit e = SV bit 3+e <-> qubit 6-e
#pragma unroll
      for (int e = 0; e < 3; ++e) {
        const float* G = gl + qb[e] * 8;
        const float h00 = G[0], h01x = G[2], h01y = G[3], h10x = G[4],
                    h10y = G[5], h11x = G[6], h11y = G[7];
        const int m = 1 << e;
#pragma unroll
        for (int r = 0; r < 8; ++r)
          if (!(r & m))
            pbfly(vre[r], vim[r], vre[r | m], vim[r | m], h00, h01x, h01y,
                  h10x, h10y, h11x, h11y);
      }
    }
#pragma unroll
    for (int r = 0; r < 8; ++r) {
      uint2 b;
      b.x = pk2(vre[r].x, vre[r].y);
      b.y = pk2(vim[r].x, vim[r].y);
      *(uint2*)&sc[tc2 ^ CC2[r]] = b;
    }

    // ======== RT3 (layout C); reg bits = SV bits 0-2, + bit-9 gate.
#pragma unroll
    for (int r = 0; r < 8; ++r) {
      const uint2 b = *(const uint2*)&sc[tc3 ^ CC3[r]];
      vre[r] = up2(b.x);
      vim[r] = up2(b.y);
    }
    {
      const int qb[3] = {9, 8, 7};  // reg bit e = SV bit e <-> qubit 9-e
#pragma unroll
      for (int e = 0; e < 3; ++e) {
        const float* G = gl + qb[e] * 8;
        const float h00 = G[0], h01x = G[2], h01y = G[3], h10x = G[4],
                    h10y = G[5], h11x = G[6], h11y = G[7];
        const int m = 1 << e;
#pragma unroll
        for (int r = 0; r < 8; ++r)
          if (!(r & m))
            pbfly(vre[r], vim[r], vre[r | m], vim[r | m], h00, h01x, h01y,
                  h10x, h10y, h11x, h11y);
      }
    }
    {  // qubit-0 gate on SV bit 9 = pack halves (.x <-> .y), scalar form.
      const float* G = gl + 0 * 8;
      const float h00 = G[0], h01x = G[2], h01y = G[3], h10x = G[4],
                  h10y = G[5], h11x = G[6], h11y = G[7];
#pragma unroll
      for (int r = 0; r < 8; ++r) {
        const float re0 = vre[r].x, im0 = vim[r].x;
        const float re1 = vre[r].y, im1 = vim[r].y;
        vre[r].x = h00 * re0 + h01x * re1 - h01y * im1;
        vim[r].x = h00 * im0 + h01x * im1 + h01y * re1;
        vre[r].y = h10x * re0 - h10y * im0 + h11x * re1 - h11y * im1;
        vim[r].y = h10x * im0 + h10y * re0 + h11x * im1 + h11y * re1;
      }
    }
    if (l != 0) {
      // write layout A: state p=r|(t<<3) at 2A+h; partner differs by ^513.
#pragma unroll
      for (int r = 0; r < 8; ++r) {
        const int w0 = ta3 ^ CWA[r];
        sc[w0] = pk2(vre[r].x, vim[r].x);
        sc[w0 ^ 513] = pk2(vre[r].y, vim[r].y);
      }
    }
  }

  // ---- output: reals only. .x -> indices 8t..8t+7, .y -> +512.
  const size_t ob = (size_t)sv * 1024 + 8 * t;
  if (ob + 8 <= (size_t)out_size) {
    *(float4*)(out + ob) = make_float4(vre[0].x, vre[1].x, vre[2].x, vre[3].x);
    *(float4*)(out + ob + 4) =
        make_float4(vre[4].x, vre[5].x, vre[6].x, vre[7].x);
  }
  if (ob + 512 + 8 <= (size_t)out_size) {
    *(float4*)(out + ob + 512) =
        make_float4(vre[0].y, vre[1].y, vre[2].y, vre[3].y);
    *(float4*)(out + ob + 516) =
        make_float4(vre[4].y, vre[5].y, vre[6].y, vre[7].y);
  }
}

extern "C" void kernel_launch(void* const* d_in, const int* in_sizes, int n_in,
                              void* d_out, int out_size, void* d_ws, size_t ws_size,
                              hipStream_t stream) {
  const float* x = (const float*)d_in[0];   // [128,16,32,32] f32
  const float* w = (const float*)d_in[1];   // [5,10,3] f32
  float* out = (float*)d_out;               // f32 (real part of complex64)
  float* gw = (float*)d_ws;                 // 50 gates x 8 floats = 1600 B
  const int nstates = in_sizes[0] / 1024;   // 2048
  build_gates<<<1, 64, 0, stream>>>(w, gw);
  qc_apply<<<nstates, NTH, 0, stream>>>(x, gw, out, out_size);
}

// Round 13
// 80.482 us; speedup vs baseline: 1.0602x; 1.0227x over previous
//
#include <hip/hip_runtime.h>
#include <hip/hip_fp16.h>

// out[s,i] = Re( U x_s ), reverse-order transposed-gate statevector sim.
// R13 = R12 (passing) with the gate path moved into LDS:
//  - gates built in-kernel (lanes<50, __sinf/__cosf) into sg[400] (LDS),
//    removing the build_gates dispatch and ALL global gate loads
//  - gate coefficient reads are uniform ds_read broadcasts -> no more
//    s_load/lgkmcnt coupling draining the DS pipeline at every gate level.
// Everything else (layouts, sigma fold, SoA pack on bit 9, f16 LDS state,
// barrier-free single-wave blocks) is byte-identical to R12.

#define NQ 10
#define NL 5
#define NTH 64

typedef float f2 __attribute__((ext_vector_type(2)));
typedef unsigned int u32;

// ----- composed reversed ring-CNOT permutation (verified R3-R12), linear.
constexpr int csigma(int i) {
  for (int q = 0; q < NQ; ++q) {
    const int cb = 9 - q, tb = 9 - ((q + 1) % NQ);
    i ^= ((i >> cb) & 1) << tb;
  }
  return i;
}

// Layout-A block index (9 bits, linear, kernel {0,511}):
constexpr int cA(int s) {
  return ((s ^ (s >> 4)) & 1) | ((((s >> 1) ^ (s >> 5)) & 1) << 1) |
         ((((s >> 2) ^ (s >> 6)) & 1) << 2) |
         ((((s >> 3) ^ (s >> 7)) & 1) << 3) |
         ((((s >> 4) ^ (s >> 8)) & 1) << 4) | (((s ^ (s >> 1)) & 1) << 5) |
         ((((s >> 1) ^ (s >> 2)) & 1) << 6) |
         ((((s >> 2) ^ (s >> 3)) & 1) << 7) | (((s >> 9) & 1) << 8);
}
// Layout-C block index (linear, bijective on 9 bits):
constexpr int cC(int p) {
  return ((p >> 6) & 7) | (((p ^ (p >> 3)) & 1) << 3) |
         ((((p >> 1) ^ (p >> 4)) & 1) << 4) | (((p >> 2) & 1) << 5) |
         (((p >> 3) & 1) << 6) | (((p >> 4) & 1) << 7) | (((p >> 5) & 1) << 8);
}

// packed SoA butterfly: two independent complex bflys, component-wise.
__device__ __forceinline__ void pbfly(f2& aRe, f2& aIm, f2& bRe, f2& bIm,
                                      float h00, float h01x, float h01y,
                                      float h10x, float h10y, float h11x,
                                      float h11y) {
  const f2 naRe = h00 * aRe + h01x * bRe - h01y * bIm;
  const f2 naIm = h00 * aIm + h01x * bIm + h01y * bRe;
  const f2 nbRe = h10x * aRe - h10y * aIm + h11x * bRe - h11y * bIm;
  const f2 nbIm = h10x * aIm + h10y * aRe + h11x * bIm + h11y * bRe;
  aRe = naRe; aIm = naIm; bRe = nbRe; bIm = nbIm;
}

__device__ __forceinline__ u32 pk2(float a, float b) {
  __half2 h = __floats2half2_rn(a, b);
  return *(u32*)&h;
}
__device__ __forceinline__ f2 up2(u32 u) {
  __half2 h = *(__half2*)&u;
  return (f2){__low2float(h), __high2float(h)};
}

__global__ __launch_bounds__(NTH) void qc_apply(
    const float* __restrict__ x, const float* __restrict__ wts,
    float* __restrict__ out, int out_size) {
  __shared__ alignas(16) u32 sc[1024];   // 512 blocks x 2 words (f16x2 each)
  __shared__ alignas(16) float sg[NL * NQ * 8];  // gate table, f32

  const int t = threadIdx.x;
  const int sv = blockIdx.x;

  // ---- in-kernel gate build (lanes < 50): transposed U3, h00 real.
  // Same-wave DS ordering: these ds_writes precede all sg reads in program
  // order -> visible without a barrier (validated by R12's barrier-free pass).
  if (t < NL * NQ) {
    const float th = wts[t * 3 + 0], ph = wts[t * 3 + 1], lm = wts[t * 3 + 2];
    const float ch_ = __cosf(0.5f * th), sh = __sinf(0.5f * th);
    const float cl = __cosf(lm), sl = __sinf(lm);
    const float cp = __cosf(ph), sp = __sinf(ph);
    const float cpl = __cosf(ph + lm), spl = __sinf(ph + lm);
    float* G = sg + t * 8;
    G[0] = ch_;       G[1] = 0.0f;
    G[2] = cp * sh;   G[3] = sp * sh;
    G[4] = -cl * sh;  G[5] = -sl * sh;
    G[6] = cpl * ch_; G[7] = spl * ch_;
  }

  // ---- runtime sigma(t) and hoisted address bases (identical to R12).
  int st = t;
#pragma unroll
  for (int q = 0; q < NQ; ++q) {
    const int cb = 9 - q, tb = 9 - ((q + 1) % NQ);
    st ^= ((st >> cb) & 1) << tb;
  }
  const int baseS = cA(st) << 1;                 // sigma-read base (layout A)
  const int tb1 = t << 1;                        // RT1-write base (layout B)
  const int tb2 = (((t & 7) | ((t >> 3) << 6)) ^ ((((t >> 3) & 3)) << 3)) << 1;
  const int tc2 = cC((t & 7) | ((t >> 3) << 6)) << 1;  // RT2-write base (C)
  const int tc3 = cC(t << 3) << 1;               // RT3-read base (C)
  const int ta3 = cA(t << 3) << 1;               // RT3-write base (A)

  static constexpr int SRC[8] = {
      cA(csigma(0 << 6)) << 1, cA(csigma(1 << 6)) << 1, cA(csigma(2 << 6)) << 1,
      cA(csigma(3 << 6)) << 1, cA(csigma(4 << 6)) << 1, cA(csigma(5 << 6)) << 1,
      cA(csigma(6 << 6)) << 1, cA(csigma(7 << 6)) << 1};
#define CB1v(r) ((((r) << 6) ^ (((r) & 3) << 3)) << 1)
  static constexpr int CB1[8] = {CB1v(0), CB1v(1), CB1v(2), CB1v(3),
                                 CB1v(4), CB1v(5), CB1v(6), CB1v(7)};
  static constexpr int CC2[8] = {cC(0 << 3) << 1, cC(1 << 3) << 1,
                                 cC(2 << 3) << 1, cC(3 << 3) << 1,
                                 cC(4 << 3) << 1, cC(5 << 3) << 1,
                                 cC(6 << 3) << 1, cC(7 << 3) << 1};
  static constexpr int CC3[8] = {cC(0) << 1, cC(1) << 1, cC(2) << 1,
                                 cC(3) << 1, cC(4) << 1, cC(5) << 1,
                                 cC(6) << 1, cC(7) << 1};
  static constexpr int CWA[8] = {
      (cA(0) << 1) | 0, (cA(1) << 1) | 1, (cA(2) << 1) | 0, (cA(3) << 1) | 1,
      (cA(4) << 1) | 0, (cA(5) << 1) | 1, (cA(6) << 1) | 0, (cA(7) << 1) | 1};
  static constexpr int CAj[16] = {cA(0),  cA(1),  cA(2),  cA(3),
                                  cA(4),  cA(5),  cA(6),  cA(7),
                                  cA(8),  cA(9),  cA(10), cA(11),
                                  cA(12), cA(13), cA(14), cA(15)};

  // ---- init: x real -> layout A f16 (state s at word 2*A(s)+h(s), h=s0^s9).
  {
    const float* xs = x + (size_t)sv * 1024;
    float4 xv[4];
#pragma unroll
    for (int i4 = 0; i4 < 4; ++i4) xv[i4] = ((const float4*)xs)[4 * t + i4];
    const int ib2 = cA(16 * t) << 1;
    const int ihb = (t >> 5) & 1;  // h(16t) = s9 = t5
#pragma unroll
    for (int j = 0; j < 16; ++j) {
      const float xj = ((const float*)xv)[j];
      const int word = (ib2 ^ (CAj[j] << 1)) | (ihb ^ (j & 1));
      sc[word] = pk2(xj, 0.0f);
    }
  }

  f2 vre[8], vim[8];

  for (int l = NL - 1; l >= 0; --l) {
    const float* gl = sg + l * NQ * 8;   // LDS pointer: uniform ds_read bcast

    // ======== RT1: sigma-gather (layout A); reg bits = SV bits 6-8.
#pragma unroll
    for (int r = 0; r < 8; ++r) {
      const uint2 b = *(const uint2*)&sc[baseS ^ SRC[r]];
      const f2 lo = up2(b.x);
      const f2 hi = up2(b.y);
      vre[r] = (f2){lo.x, hi.x};
      vim[r] = (f2){lo.y, hi.y};
    }
    {
      const int qb[3] = {3, 2, 1};  // reg bit e = SV bit 6+e <-> qubit 3-e
#pragma unroll
      for (int e = 0; e < 3; ++e) {
        const float* G = gl + qb[e] * 8;
        const float h00 = G[0], h01x = G[2], h01y = G[3], h10x = G[4],
                    h10y = G[5], h11x = G[6], h11y = G[7];
        const int m = 1 << e;
#pragma unroll
        for (int r = 0; r < 8; ++r)
          if (!(r & m))
            pbfly(vre[r], vim[r], vre[r | m], vim[r | m], h00, h01x, h01y,
                  h10x, h10y, h11x, h11y);
      }
    }
#pragma unroll
    for (int r = 0; r < 8; ++r) {
      uint2 b;
      b.x = pk2(vre[r].x, vre[r].y);
      b.y = pk2(vim[r].x, vim[r].y);
      *(uint2*)&sc[tb1 ^ CB1[r]] = b;
    }

    // ======== RT2 (layout B -> C); reg bits = SV bits 3-5.
#pragma unroll
    for (int r = 0; r < 8; ++r) {
      const uint2 b = *(const uint2*)&sc[tb2 ^ (r << 4)];
      vre[r] = up2(b.x);
      vim[r] = up2(b.y);
    }
    {
      const int qb[3] = {6, 5, 4};  // reg bit e = SV bit 3+e <-> qubit 6-e
#pragma unroll
      for (int e = 0; e < 3; ++e) {
        const float* G = gl + qb[e] * 8;
        const float h00 = G[0], h01x = G[2], h01y = G[3], h10x = G[4],
                    h10y = G[5], h11x = G[6], h11y = G[7];
        const int m = 1 << e;
#pragma unroll
        for (int r = 0; r < 8; ++r)
          if (!(r & m))
            pbfly(vre[r], vim[r], vre[r | m], vim[r | m], h00, h01x, h01y,
                  h10x, h10y, h11x, h11y);
      }
    }
#pragma unroll
    for (int r = 0; r < 8; ++r) {
      uint2 b;
      b.x = pk2(vre[r].x, vre[r].y);
      b.y = pk2(vim[r].x, vim[r].y);
      *(uint2*)&sc[tc2 ^ CC2[r]] = b;
    }

    // ======== RT3 (layout C); reg bits = SV bits 0-2, + bit-9 gate.
#pragma unroll
    for (int r = 0; r < 8; ++r) {
      const uint2 b = *(const uint2*)&sc[tc3 ^ CC3[r]];
      vre[r] = up2(b.x);
      vim[r] = up2(b.y);
    }
    {
      const int qb[3] = {9, 8, 7};  // reg bit e = SV bit e <-> qubit 9-e
#pragma unroll
      for (int e = 0; e < 3; ++e) {
        const float* G = gl + qb[e] * 8;
        const float h00 = G[0], h01x = G[2], h01y = G[3], h10x = G[4],
                    h10y = G[5], h11x = G[6], h11y = G[7];
        const int m = 1 << e;
#pragma unroll
        for (int r = 0; r < 8; ++r)
          if (!(r & m))
            pbfly(vre[r], vim[r], vre[r | m], vim[r | m], h00, h01x, h01y,
                  h10x, h10y, h11x, h11y);
      }
    }
    {  // qubit-0 gate on SV bit 9 = pack halves (.x <-> .y), scalar form.
      const float* G = gl + 0 * 8;
      const float h00 = G[0], h01x = G[2], h01y = G[3], h10x = G[4],
                  h10y = G[5], h11x = G[6], h11y = G[7];
#pragma unroll
      for (int r = 0; r < 8; ++r) {
        const float re0 = vre[r].x, im0 = vim[r].x;
        const float re1 = vre[r].y, im1 = vim[r].y;
        vre[r].x = h00 * re0 + h01x * re1 - h01y * im1;
        vim[r].x = h00 * im0 + h01x * im1 + h01y * re1;
        vre[r].y = h10x * re0 - h10y * im0 + h11x * re1 - h11y * im1;
        vim[r].y = h10x * im0 + h10y * re0 + h11x * im1 + h11y * re1;
      }
    }
    if (l != 0) {
#pragma unroll
      for (int r = 0; r < 8; ++r) {
        const int w0 = ta3 ^ CWA[r];
        sc[w0] = pk2(vre[r].x, vim[r].x);
        sc[w0 ^ 513] = pk2(vre[r].y, vim[r].y);
      }
    }
  }

  // ---- output: reals only. .x -> indices 8t..8t+7, .y -> +512.
  const size_t ob = (size_t)sv * 1024 + 8 * t;
  if (ob + 8 <= (size_t)out_size) {
    *(float4*)(out + ob) = make_float4(vre[0].x, vre[1].x, vre[2].x, vre[3].x);
    *(float4*)(out + ob + 4) =
        make_float4(vre[4].x, vre[5].x, vre[6].x, vre[7].x);
  }
  if (ob + 512 + 8 <= (size_t)out_size) {
    *(float4*)(out + ob + 512) =
        make_float4(vre[0].y, vre[1].y, vre[2].y, vre[3].y);
    *(float4*)(out + ob + 516) =
        make_float4(vre[4].y, vre[5].y, vre[6].y, vre[7].y);
  }
}

extern "C" void kernel_launch(void* const* d_in, const int* in_sizes, int n_in,
                              void* d_out, int out_size, void* d_ws, size_t ws_size,
                              hipStream_t stream) {
  const float* x = (const float*)d_in[0];   // [128,16,32,32] f32
  const float* w = (const float*)d_in[1];   // [5,10,3] f32
  float* out = (float*)d_out;               // f32 (real part of complex64)
  const int nstates = in_sizes[0] / 1024;   // 2048
  qc_apply<<<nstates, NTH, 0, stream>>>(x, w, out, out_size);
}